// Round 9
// baseline (138.350 us; speedup 1.0000x reference)
//
#include <hip/hip_runtime.h>
#include <stdint.h>

#define HW 9216
#define CDIM 128
#define WIDTH 96
#define BATCH 2
#define SPLITS 48           // 48 key-splits -> 48 partial streams
#define KSPLIT 192          // keys per split; LDS = 192*256B = 48 KB -> 3 blocks/CU
#define NKG 6               // 192 / 32 keys per key-group
#define QTILE 128           // q-rows per block (4 waves x 32q)
#define NQT (HW / QTILE)    // 72 q-tiles
#define NWG (NQT * SPLITS * BATCH)   // 6912 blocks = 8 x 864

// Logits: w = dot * QSCALE, e = (e^w)^2 = exp(dot/(0.1*sqrt(128))).
// |dot|<=1 -> |w|<=0.442: packed Taylor-4 + square, rel err ~3e-4 (<< f16 noise).
#define QSCALE 0.44194173824159216f
// conf numerator: exp(2*mx) = exp2(mx * 2/ln2)
#define MXSCALE 2.8853900817779268f

typedef _Float16 half8 __attribute__((ext_vector_type(8)));
typedef float f32x16 __attribute__((ext_vector_type(16)));
typedef float float2v __attribute__((ext_vector_type(2)));

// ---------------------------------------------------------------------------
// Kernel 1: L2-normalize over C, write fp16 [B][HW][C] (unchanged).
// ---------------------------------------------------------------------------
__global__ __launch_bounds__(256) void norm_kernel(const float* __restrict__ fL,
                                                   const float* __restrict__ fR,
                                                   _Float16* __restrict__ Qh,
                                                   _Float16* __restrict__ Kh)
{
    __shared__ float ssred[4][64];
    __shared__ _Float16 ot[64 * 130];   // +2 halves pad -> bank advance 1/row

    const float* src = (blockIdx.y == 0) ? fL : fR;
    _Float16* dst    = (blockIdx.y == 0) ? Qh : Kh;
    const float outScale = (blockIdx.y == 0) ? QSCALE : 1.0f;

    const int t = threadIdx.x;
    const int pos_l = t & 63, cg = t >> 6;            // 4 channel groups of 32
    const int pos0 = blockIdx.x * 64;                  // 64 | HW so no straddle
    const int b = pos0 / HW, pos_in = pos0 % HW + pos_l;

    const float* p = src + (size_t)b * CDIM * HW + pos_in;

    float v[32];
    float ss = 0.f;
    #pragma unroll
    for (int j = 0; j < 32; ++j) {
        v[j] = p[(size_t)(cg * 32 + j) * HW];
        ss += v[j] * v[j];
    }
    ssred[cg][pos_l] = ss;
    __syncthreads();
    float tot = ssred[0][pos_l] + ssred[1][pos_l] + ssred[2][pos_l] + ssred[3][pos_l];
    float scale = outScale / fmaxf(sqrtf(tot), 1e-6f);

    #pragma unroll
    for (int j = 0; j < 32; ++j)
        ot[pos_l * 130 + cg * 32 + j] = (_Float16)(v[j] * scale);
    __syncthreads();

    uint4* og = (uint4*)(dst + (size_t)(b * HW + pos0 % HW + 0) * CDIM);
    #pragma unroll
    for (int i = 0; i < 4; ++i) {
        int idx = i * 256 + t;            // 0..1023 dwordx4 slots
        int row = idx >> 4, chunk = idx & 15;
        og[idx] = *(const uint4*)&ot[row * 130 + chunk * 8];
    }
}

// ---------------------------------------------------------------------------
// Kernel 2: fused correlation + softmax-accumulate — persistent-K +
// EXPLICIT 2-DEEP ACCUMULATOR PIPELINE (T15, static names per rule #20).
//   r7 evidence: VGPR_Count=68 = qf(32)+acc(16)+E2(16) exactly -> compiler
//   allocates minimum regs and runs each kg fully serial per wave:
//   ds_read -> 280cy dependent MFMA chain (wave stalled) -> 270cy epilogue
//   -> repeat = ~1067 cy/quantum vs ~290 floor. kgs are independent, so:
//   ping-pong accA/accB; issue CHAIN(kg+1), sched_barrier(0), then EPI(kg)
//   VALU runs while kg+1's MFMAs execute in the matrix pipe.
//   Geometry = r7 (proven): KSPLIT 192, 48 KB LDS staged once, 3 blocks/CU,
//   1 qset/wave, 6912 blocks, XCD-chunked with qt fastest.
//   r8's fused combine REVERTED: cross-XCD part reads via normal loads are
//   not coherent (absmax 5.5) — Guideline 16. 3-kernel structure restored.
//   Checks: VGPR should RISE to ~100-130 (double-buffer tell); WRITE_SIZE
//   ~14.2 MB (spill signature would be >>20).
// ---------------------------------------------------------------------------
__global__ __launch_bounds__(256, 3) void attn_kernel(const _Float16* __restrict__ Qh,
                                                      const _Float16* __restrict__ Kh,
                                                      float4* __restrict__ part)
{
    __shared__ __align__(16) _Float16 Ks[KSPLIT * 128];   // 48 KB, staged once

    // bijective XCD swizzle (NWG % 8 == 0): xcd = wg & 7 gets chunk of 864;
    // qt fastest within a chunk -> each XCD's K-split stays L2-hot.
    const int wg0 = blockIdx.x;
    const int nid = (wg0 & 7) * (NWG / 8) + (wg0 >> 3);
    const int qt = nid % NQT;
    const int sb = nid / NQT;                  // 0..95
    const int split = sb % SPLITS;
    const int b = sb / SPLITS;

    const int t = threadIdx.x;
    const int lane = t & 63, wave = t >> 6;        // 4 waves
    const int lane31 = lane & 31, hi = lane >> 5;
    const int ln15 = lane & 15, qd = lane >> 4;

    const char* kp0 = (const char*)(Kh + (size_t)b * HW * CDIM) +
                      (size_t)(split * KSPLIT) * (CDIM * 2);

    // ---- stage the whole K-split: wave stages rows [wave*48, wave*48+48) ----
    // 12 DMAs x (4 rows x 256B). LDS dest linear; source 16B-chunk
    // XOR-swizzled: LDS[r][c] = K[r][c ^ (r&15)]. wave*48 % 16 == 0, so
    // (r&15) has period 4 in DMA index i: 4 base voffsets + i*1024.
    {
        int voff4[4];
        #pragma unroll
        for (int i = 0; i < 4; ++i) {
            int r = wave * 48 + i * 4 + qd;
            voff4[i] = r * 256 + ((ln15 ^ (r & 15)) << 4) - i * 1024;
        }
        _Float16* db = &Ks[wave * (48 * 128)];
        #pragma unroll
        for (int i = 0; i < 12; ++i)
            __builtin_amdgcn_global_load_lds(
                (const __attribute__((address_space(1))) uint32_t*)(kp0 + voff4[i & 3] + i * 1024),
                (__attribute__((address_space(3))) uint32_t*)(db + i * 512),
                16, 0, 0);
    }

    // ---- Q fragments (B-operand): col = lane31 = q-row, k = hi*8+j ----
    half8 qf[8];
    {
        const char* qb = (const char*)(Qh +
            ((size_t)(b * HW + qt * QTILE + wave * 32 + lane31)) * CDIM);
        #pragma unroll
        for (int kc = 0; kc < 8; ++kc)
            qf[kc] = *(const half8*)(qb + kc * 32 + hi * 16);
    }

    // K-frag (A-operand) LDS byte offsets: row = lane31, chunk (kc*2+hi)
    // un-swizzled via ^ln15. kg adds kg*8192.
    int rdoff[8];
    #pragma unroll
    for (int kc = 0; kc < 8; ++kc)
        rdoff[kc] = (lane31 << 8) + ((((kc << 1) | hi) ^ ln15) << 4);

    // coordinates: key = split*192 + kg*32 + crow + 4hi; split*192 % 96 == 0
    // -> x = 32*(kg%3) + crow + 4hi (never wraps), y = split*2 + kg/3.
    const float ysp = (float)(split * 2);

    float2v E2[8];                       // per reg-pair e-sums (crow fold deferred)
    #pragma unroll
    for (int p = 0; p < 8; ++p) E2[p] = (float2v)0.f;
    float mxs = -1.0e30f;
    float2v axb2 = (float2v)0.f, ay2 = (float2v)0.f;

    const char* ksb = (const char*)&Ks[0];
    const float2v C4 = (float2v)(1.0f / 24.0f), C3 = (float2v)(1.0f / 6.0f),
                  C2 = (float2v)0.5f, C1 = (float2v)1.0f;

    __syncthreads();   // K fully staged (single vmcnt(0) drain of the run)

    // ---- 2-deep pipelined main loop over 6 independent key-groups ----
    #define CHAIN(ACC, KG)                                                       \
        {                                                                        \
            __builtin_amdgcn_s_setprio(1);                                       \
            _Pragma("unroll")                                                    \
            for (int kc = 0; kc < 8; ++kc) {                                     \
                half8 kf = *(const half8*)(ksb + (KG) * 8192 + rdoff[kc]);       \
                ACC = __builtin_amdgcn_mfma_f32_32x32x16_f16(                    \
                    kf, qf[kc], (kc == 0) ? (f32x16)0.f : ACC, 0, 0, 0);         \
            }                                                                    \
            __builtin_amdgcn_s_setprio(0);                                       \
        }

    #define EPI(ACC, KG)                                                         \
        {                                                                        \
            const float xb = (float)(32 * ((KG) % 3));                           \
            const float yk = ysp + (float)((KG) / 3);                            \
            float2v lt2;                                                         \
            _Pragma("unroll")                                                    \
            for (int p = 0; p < 8; ++p) {                                        \
                float2v w;                                                       \
                w.x = ACC[2 * p];                                                \
                w.y = ACC[2 * p + 1];                                            \
                mxs = fmaxf(mxs, fmaxf(w.x, w.y));   /* v_max3-fusable */        \
                float2v h = w * C4 + C3;             /* e^w Taylor-4 */          \
                h = h * w + C2;                                                  \
                h = h * w + C1;                                                  \
                h = h * w + C1;                                                  \
                float2v e = h * h;                                               \
                E2[p] += e;                                                      \
                lt2 = (p == 0) ? e : (lt2 + e);                                  \
            }                                                                    \
            axb2 += lt2 * (float2v)xb;                                           \
            ay2  += lt2 * (float2v)yk;                                           \
        }

    f32x16 accA, accB;
    CHAIN(accA, 0)
    CHAIN(accB, 1) __builtin_amdgcn_sched_barrier(0); EPI(accA, 0)
    CHAIN(accA, 2) __builtin_amdgcn_sched_barrier(0); EPI(accB, 1)
    CHAIN(accB, 3) __builtin_amdgcn_sched_barrier(0); EPI(accA, 2)
    CHAIN(accA, 4) __builtin_amdgcn_sched_barrier(0); EPI(accB, 3)
    CHAIN(accB, 5) __builtin_amdgcn_sched_barrier(0); EPI(accA, 4)
    EPI(accB, 5)
    #undef CHAIN
    #undef EPI

    // ---- per-lane fold: apply compile-time crow weights once ----
    float l = 0.f, axc = 0.f;
    #pragma unroll
    for (int p = 0; p < 8; ++p) {
        const float c0 = (float)(((2 * p) & 3) + 8 * ((2 * p) >> 2)); // 0,2,8,...,26
        l   += E2[p].x + E2[p].y;
        axc += c0 * E2[p].x + (c0 + 1.0f) * E2[p].y;
    }
    float ax = axc + (float)(4 * hi) * l + axb2.x + axb2.y;
    float ay = ay2.x + ay2.y;
    float mx = mxs;

    // combine hi/lo key-halves (lanes l and l+32 share q = lane31)
    l  += __shfl_xor(l, 32, 64);
    ax += __shfl_xor(ax, 32, 64);
    ay += __shfl_xor(ay, 32, 64);
    mx  = fmaxf(mx, __shfl_xor(mx, 32, 64));

    if (hi == 0) {
        int row = qt * QTILE + wave * 32 + lane31;
        part[(size_t)split * (BATCH * HW) + b * HW + row] =
            make_float4(l, ax, ay, __builtin_amdgcn_exp2f(mx * MXSCALE));
    }
}

// ---------------------------------------------------------------------------
// Kernel 3: combine 48 partials per query row, write flow + conf
// ---------------------------------------------------------------------------
__global__ __launch_bounds__(256) void combine_kernel(const float4* __restrict__ part,
                                                      float* __restrict__ out)
{
    int tid = blockIdx.x * 256 + threadIdx.x;   // 0 .. B*HW-1 (grid sized exactly)
    int b = tid / HW, pos = tid % HW;
    float l = 0.f, ax = 0.f, ay = 0.f, mx = 0.f;
    #pragma unroll
    for (int s = 0; s < SPLITS; ++s) {
        float4 v = part[(size_t)s * (BATCH * HW) + tid];   // coalesced
        l += v.x; ax += v.y; ay += v.z; mx = fmaxf(mx, v.w);
    }
    float inv = 1.0f / l;
    int x = pos % WIDTH, y = pos / WIDTH;
    out[(size_t)b * 2 * HW + pos]           = ax * inv - (float)x;
    out[(size_t)b * 2 * HW + HW + pos]      = ay * inv - (float)y;
    out[(size_t)BATCH * 2 * HW + (size_t)b * HW + pos] = mx * inv;
}

// ---------------------------------------------------------------------------
extern "C" void kernel_launch(void* const* d_in, const int* in_sizes, int n_in,
                              void* d_out, int out_size, void* d_ws, size_t ws_size,
                              hipStream_t stream)
{
    const float* fL = (const float*)d_in[0];
    const float* fR = (const float*)d_in[1];
    float* out = (float*)d_out;

    char* ws = (char*)d_ws;
    const size_t QH_BYTES = (size_t)BATCH * HW * CDIM * sizeof(_Float16);  // 4.72 MB
    _Float16* Qh  = (_Float16*)ws;
    _Float16* Kh  = (_Float16*)(ws + QH_BYTES);
    float4*   part = (float4*)(ws + 2 * QH_BYTES);                         // 14.16 MB

    norm_kernel<<<dim3((BATCH * HW) / 64, 2), 256, 0, stream>>>(fL, fR, Qh, Kh);
    attn_kernel<<<dim3(NWG), 256, 0, stream>>>(Qh, Kh, part);
    combine_kernel<<<dim3((BATCH * HW) / 256), 256, 0, stream>>>(part, out);
}